// Round 2
// 139.766 us; speedup vs baseline: 1.0017x; 1.0017x over previous
//
#include <hip/hip_runtime.h>
#include <stdint.h>

#define BB 4
#define CC 256
#define NN 4096   // H*W = 64*64
#define RR 32
#define NCHUNK 8
#define JSTEPS (NN / NCHUNK / 32)   // 16
#define CSIZE  (NN / NCHUNK)        // 512

typedef __attribute__((ext_vector_type(8)))  short  short8;   // 8 bf16 (MFMA A/B frag)
typedef __attribute__((ext_vector_type(4)))  short  short4v;  // 4 bf16 = 8B
typedef __attribute__((ext_vector_type(16))) float  floatx16; // MFMA C/D frag

#if defined(__has_builtin)
#if __has_builtin(__builtin_amdgcn_cvt_pk_bf16_f32)
#define HAVE_PK_BF16 1
#endif
#endif

#ifdef HAVE_PK_BF16
typedef __attribute__((ext_vector_type(2))) __bf16 bf16x2;
#endif

static __device__ __forceinline__ unsigned short f2bf_sw(float f) {
    union { float f; unsigned int u; } v; v.f = f;
    unsigned int u = v.u;
    u += 0x7fffu + ((u >> 16) & 1u);
    return (unsigned short)(u >> 16);
}

// pack two fp32 -> bf16x2 in one HW inst (lo = a, hi = b)
static __device__ __forceinline__ unsigned int pk_bf16(float a, float b) {
#ifdef HAVE_PK_BF16
    bf16x2 r = __builtin_amdgcn_cvt_pk_bf16_f32(a, b);
    unsigned int u; __builtin_memcpy(&u, &r, 4); return u;
#else
    return (unsigned int)f2bf_sw(a) | ((unsigned int)f2bf_sw(b) << 16);
#endif
}

static __device__ __forceinline__ unsigned short f2bf(float f) {
#ifdef HAVE_PK_BF16
    return (unsigned short)(pk_bf16(f, 0.f) & 0xffffu);
#else
    return f2bf_sw(f);
#endif
}

static __device__ __forceinline__ float bf2f(unsigned short u) {
    union { unsigned int u; float f; } v; v.u = ((unsigned int)u) << 16;
    return v.f;
}

static __device__ __forceinline__ float exp2_fast(float x) {
#if __has_builtin(__builtin_amdgcn_exp2f)
    return __builtin_amdgcn_exp2f(x);
#else
    return exp2f(x);
#endif
}

// ---------------- K1: depthwise 3x3, all 3 dilations -> D bf16 --------------
// grid (C, B), block 256 = 4 waves; wave = 16-h strip, lane = w. 26 x-rows in
// registers (x read exactly once); horizontal taps via shfl (CSE'd per phase).
// D layout: [p][b][c][n] bf16.
__global__ __launch_bounds__(256, 4) void k_dw(
    const float* __restrict__ x,
    const float* __restrict__ w1, const float* __restrict__ b1,
    const float* __restrict__ w2, const float* __restrict__ b2,
    const float* __restrict__ w3, const float* __restrict__ b3,
    unsigned short* __restrict__ Dq)
{
    int t = threadIdx.x, lane = t & 63, wv = t >> 6;
    int c = blockIdx.x, b = blockIdx.y;
    int hb = wv * 16;
    const float* xc = x + ((size_t)(b * CC + c)) * NN;
    float row[26];
    #pragma unroll
    for (int k = 0; k < 26; k++) {
        int rr = hb - 5 + k;
        int rc = rr < 0 ? 0 : (rr > 63 ? 63 : rr);
        float v = xc[rc * 64 + lane];
        row[k] = (rr >= 0 && rr <= 63) ? v : 0.f;
    }
    const float* DWW[3] = {w1, w2, w3};
    const float* DWB[3] = {b1, b2, b3};
    #pragma unroll
    for (int p = 0; p < 3; p++) {
        const int d = (p == 0) ? 1 : (p == 1 ? 3 : 5);
        float wt[9];
        #pragma unroll
        for (int q = 0; q < 9; q++) wt[q] = DWW[p][c * 9 + q];
        float bias = DWB[p][c];
        bool okl = lane >= d, okr = lane < 64 - d;
        int lml = okl ? lane - d : 0;
        int lpr = okr ? lane + d : 63;
        float sm[26], sp[26];
        #pragma unroll
        for (int k = 5 - d; k <= 20 + d; k++) {
            float a = __shfl(row[k], lml, 64); sm[k] = okl ? a : 0.f;
            float q2 = __shfl(row[k], lpr, 64); sp[k] = okr ? q2 : 0.f;
        }
        unsigned short* Dp = Dq + (((size_t)p * BB + b) * CC + c) * NN;
        #pragma unroll
        for (int hl = 0; hl < 16; hl++) {
            int k0 = hl + 5 - d, k1 = hl + 5, k2 = hl + 5 + d;
            float o = bias
                + wt[0] * sm[k0] + wt[1] * row[k0] + wt[2] * sp[k0]
                + wt[3] * sm[k1] + wt[4] * row[k1] + wt[5] * sp[k1]
                + wt[6] * sm[k2] + wt[7] * row[k2] + wt[8] * sp[k2];
            Dp[(hb + hl) * 64 + lane] = f2bf(o);
        }
    }
}

// ---------------- K2: pointwise C->R as MFMA GEMM, LDS-staged B -------------
// grid (32 ntiles of 128 n, 3 p, B), block 256 = 4 waves; wave = 32r x 32n.
// K=256 in two 128-c halves staged into LDS; A = pw bf16 (LDS-staged).
__global__ __launch_bounds__(256, 2) void k_pw(
    const unsigned short* __restrict__ Dq,
    const float* __restrict__ p1, const float* __restrict__ pb1,
    const float* __restrict__ p2, const float* __restrict__ pb2,
    const float* __restrict__ p3, const float* __restrict__ pb3,
    unsigned short* __restrict__ V, unsigned short* __restrict__ Qt,
    unsigned short* __restrict__ Kt)
{
    __shared__ unsigned short PW[32 * 264];        // pw bf16, row stride 264
    __shared__ unsigned short Dt[128 * 132];       // D half-tile [c128][n128], pad 4
    __shared__ unsigned short Lt[4][32][40];       // per-wave [n][r] transpose buffer
    int t = threadIdx.x, lane = t & 63, l31 = lane & 31, h = lane >> 5, wv = t >> 6;
    int ntile = blockIdx.x, p = blockIdx.y, b = blockIdx.z;
    const float* pw  = (p == 0) ? p1  : (p == 1 ? p2  : p3);
    const float* pwb = (p == 0) ? pb1 : (p == 1 ? pb2 : pb3);

    // stage pw -> bf16 LDS: thread r = t>>3, 32-col block (t&7)*32
    {
        int r = t >> 3, cb0 = (t & 7) * 32;
        const float4* src = (const float4*)(pw + r * CC + cb0);
        #pragma unroll
        for (int g = 0; g < 8; g++) {
            float4 f = src[g];
            union { short4v s; unsigned int u[2]; } s4;
            s4.u[0] = pk_bf16(f.x, f.y);
            s4.u[1] = pk_bf16(f.z, f.w);
            *(short4v*)&PW[r * 264 + cb0 + g * 4] = s4.s;
        }
    }
    __syncthreads();

    int n = ntile * 128 + wv * 32 + l31;
    const size_t dbase = ((size_t)p * BB + b) * CC * (size_t)NN;
    int cr = t >> 1, nseg = (t & 1) * 64;          // staging: row cr, 64-n segment
    floatx16 acc = {};

    for (int hc = 0; hc < 2; hc++) {
        // bulk global load of this c-half's 128B/thread (coalesced, indep)
        const uint4* gsrc = (const uint4*)(Dq + dbase +
                            (size_t)(hc * 128 + cr) * NN + ntile * 128 + nseg);
        uint4 g[8];
        #pragma unroll
        for (int i = 0; i < 8; i++) g[i] = gsrc[i];
        __syncthreads();   // prior half's Dt reads complete
        {
            uint2* ldst = (uint2*)&Dt[cr * 132 + nseg];   // 8B-aligned (264B rows)
            #pragma unroll
            for (int i = 0; i < 8; i++) {
                union { uint4 q; uint2 d2[2]; } u; u.q = g[i];
                ldst[2 * i] = u.d2[0];
                ldst[2 * i + 1] = u.d2[1];
            }
        }
        __syncthreads();   // tile visible
        #pragma unroll
        for (int kt = 0; kt < 8; kt++) {
            short8 af = *(const short8*)&PW[l31 * 264 + hc * 128 + kt * 16 + 8 * h];
            short8 bf;
            #pragma unroll
            for (int j = 0; j < 8; j++)
                bf[j] = (short)Dt[(kt * 16 + 8 * h + j) * 132 + wv * 32 + l31];
            acc = __builtin_amdgcn_mfma_f32_32x32x16_bf16(af, bf, acc, 0, 0, 0);
        }
    }

    if (p == 0) {
        #pragma unroll
        for (int rr = 0; rr < 16; rr++) {
            int r = (rr & 3) + 8 * (rr >> 2) + 4 * h;          // C/D row mapping
            V[((size_t)(b * RR + r)) * NN + n] = f2bf(acc[rr] + pwb[r]);  // V[b][r][n]
        }
    } else {
        const float sc = (p == 1) ? 1.4426950408889634f : 1.f; // Q *= log2e
        unsigned short* outp = (p == 1) ? Qt : Kt;
        #pragma unroll
        for (int rr = 0; rr < 16; rr++) {
            int r = (rr & 3) + 8 * (rr >> 2) + 4 * h;
            Lt[wv][l31][r] = f2bf((acc[rr] + pwb[r]) * sc);
        }
        __threadfence_block();   // order wave-local LDS write->read (lockstep lanes)
        unsigned short* orow = outp + ((size_t)b * NN + n) * RR + h * 16;
        short8 lo = *(const short8*)&Lt[wv][l31][h * 16];
        *(short8*)orow = lo;                                   // [b][n][r], 32B/lane
        short8 hi = *(const short8*)&Lt[wv][l31][h * 16 + 8];
        *(short8*)(orow + 8) = hi;
    }
}

// ---------------- K3: fused attention, dbuf LDS V, quad-permuted frags ------
// grid (16, NCHUNK, B), block 256 = 4 waves. Each wave now owns TWO i-tiles
// (itA = bx*4+wave, itB = itA+64): K frags, V staging, barriers, and K
// prefetch amortized over 2x output. V quads stored permuted {0,2,1,3,4,6,5,7}
// so each PV B-frag is one contiguous ds_read_b128. O partials stored bf16.
__global__ __launch_bounds__(256, 2) void k_attn(
    const unsigned short* __restrict__ Qt, const unsigned short* __restrict__ Kt,
    const unsigned short* __restrict__ V, unsigned short* __restrict__ OPh,
    float* __restrict__ LP)
{
    __shared__ unsigned short Vt[2][32][36];   // double buffer
    int t = threadIdx.x;
    int wave = t >> 6, lane = t & 63, l31 = lane & 31, h = lane >> 5;
    int itA = blockIdx.x * 4 + wave;           // 0..63
    int itB = itA + 64;                        // 64..127
    int chunk = blockIdx.y;
    int b = blockIdx.z;
    int iA = itA * 32 + l31;
    int iB = itB * 32 + l31;

    const short8* qrA = (const short8*)(Qt + ((size_t)b * NN + iA) * RR);
    short8 qa1 = qrA[h], qa2 = qrA[2 + h];
    const short8* qrB = (const short8*)(Qt + ((size_t)b * NN + iB) * RR);
    short8 qb1 = qrB[h], qb2 = qrB[2 + h];

    const unsigned short* Kb = Kt + (size_t)b * NN * RR;
    const unsigned short* Vb = V + (size_t)b * RR * NN;

    int sr = t >> 3, sc = t & 7;
    int scp = (sc & 4) | ((sc & 1) << 1) | ((sc & 2) >> 1);  // {0,2,1,3,4,6,5,7}
    const unsigned short* vsrc = Vb + (size_t)sr * NN + chunk * CSIZE + sc * 4;

    floatx16 accA = {}, accB = {};
    float laccA = 0.f, laccB = 0.f;

    // prologue: stage step-0 V tile (permuted), prefetch step-1 V and step-0 K
    *(short4v*)(&Vt[0][sr][scp * 4]) = *(const short4v*)vsrc;
    short4v vnext = *(const short4v*)(vsrc + 32);
    const short8* krow0 = (const short8*)(Kb + (size_t)(chunk * CSIZE + l31) * RR);
    short8 ka1 = krow0[h], ka2 = krow0[2 + h];
    __syncthreads();

    for (int js = 0; js < JSTEPS; js++) {
        int cur = js & 1;
        if (js + 1 < JSTEPS) *(short4v*)(&Vt[1 - cur][sr][scp * 4]) = vnext;
        if (js + 2 < JSTEPS) vnext = *(const short4v*)(vsrc + (js + 2) * 32);

        // shared V B-frags for this j-step (permuted rows: contiguous b128)
        const unsigned short* vrow = &Vt[cur][l31][0];
        short8 vb1 = *(const short8*)(vrow + 8 * h);
        short8 vb2 = *(const short8*)(vrow + 16 + 8 * h);

        // ---- itile A ----
        {
            floatx16 st = {};
            st = __builtin_amdgcn_mfma_f32_32x32x16_bf16(ka1, qa1, st, 0, 0, 0);
            st = __builtin_amdgcn_mfma_f32_32x32x16_bf16(ka2, qa2, st, 0, 0, 0);
            float p[16];
            #pragma unroll
            for (int r = 0; r < 16; r++) { p[r] = exp2_fast(st[r]); laccA += p[r]; }
            union { short8 s; unsigned int u[4]; } pa1, pa2;
            #pragma unroll
            for (int r = 0; r < 8; r += 2) {
                pa1.u[r >> 1] = pk_bf16(p[r], p[r + 1]);
                pa2.u[r >> 1] = pk_bf16(p[r + 8], p[r + 9]);
            }
            accA = __builtin_amdgcn_mfma_f32_32x32x16_bf16(pa1.s, vb1, accA, 0, 0, 0);
            accA = __builtin_amdgcn_mfma_f32_32x32x16_bf16(pa2.s, vb2, accA, 0, 0, 0);
        }

        // ---- itile B (ka still live; prefetch next K after its S-MFMAs) ----
        {
            floatx16 st = {};
            st = __builtin_amdgcn_mfma_f32_32x32x16_bf16(ka1, qb1, st, 0, 0, 0);
            st = __builtin_amdgcn_mfma_f32_32x32x16_bf16(ka2, qb2, st, 0, 0, 0);
            int jn = (js + 1 < JSTEPS) ? js + 1 : js;
            const short8* krow = (const short8*)(Kb + (size_t)(chunk * CSIZE + jn * 32 + l31) * RR);
            ka1 = krow[h]; ka2 = krow[2 + h];
            float p[16];
            #pragma unroll
            for (int r = 0; r < 16; r++) { p[r] = exp2_fast(st[r]); laccB += p[r]; }
            union { short8 s; unsigned int u[4]; } pa1, pa2;
            #pragma unroll
            for (int r = 0; r < 8; r += 2) {
                pa1.u[r >> 1] = pk_bf16(p[r], p[r + 1]);
                pa2.u[r >> 1] = pk_bf16(p[r + 8], p[r + 9]);
            }
            accB = __builtin_amdgcn_mfma_f32_32x32x16_bf16(pa1.s, vb1, accB, 0, 0, 0);
            accB = __builtin_amdgcn_mfma_f32_32x32x16_bf16(pa2.s, vb2, accB, 0, 0, 0);
        }
        __syncthreads();   // reads of Vt[cur] done; Vt[1-cur] visible for js+1
    }

    // epilogue: both itiles
    {
        size_t slot = ((size_t)(b * 128 + itA) * NCHUNK + chunk) * 64 + lane;
        unsigned short* op = OPh + slot * 16;
        union { short8 s; unsigned int u[4]; } o1, o2;
        #pragma unroll
        for (int r = 0; r < 8; r += 2) {
            o1.u[r >> 1] = pk_bf16(accA[r], accA[r + 1]);
            o2.u[r >> 1] = pk_bf16(accA[r + 8], accA[r + 9]);
        }
        *(short8*)op = o1.s;
        *(short8*)(op + 8) = o2.s;
        LP[slot] = laccA;
    }
    {
        size_t slot = ((size_t)(b * 128 + itB) * NCHUNK + chunk) * 64 + lane;
        unsigned short* op = OPh + slot * 16;
        union { short8 s; unsigned int u[4]; } o1, o2;
        #pragma unroll
        for (int r = 0; r < 8; r += 2) {
            o1.u[r >> 1] = pk_bf16(accB[r], accB[r + 1]);
            o2.u[r >> 1] = pk_bf16(accB[r + 8], accB[r + 9]);
        }
        *(short8*)op = o1.s;
        *(short8*)(op + 8) = o2.s;
        LP[slot] = laccB;
    }
}

// ---------------- K4: fused merge + 1x1 conv R->C + residual ----------------
// grid (128 itiles, B), block 256. Reduce bf16 OP chunks in-register -> Ft
// tile in LDS -> 8x mfma vs LDS-staged cw -> out = x + conv + bias.
__global__ __launch_bounds__(256, 4) void k_out(
    const float* __restrict__ x, const unsigned short* __restrict__ OPh,
    const float* __restrict__ LP, const float* __restrict__ cw,
    const float* __restrict__ cb, float* __restrict__ out)
{
    __shared__ float linv[32];
    __shared__ unsigned short Ft[32][36];     // [n_local][r]
    __shared__ unsigned short CW[256 * 36];   // cw bf16, row stride 36
    int t = threadIdx.x, lane = t & 63, l31 = lane & 31, h = lane >> 5, wv = t >> 6;
    int itile = blockIdx.x, b = blockIdx.y;
    size_t base = (size_t)(b * 128 + itile) * NCHUNK;

    // stage cw -> bf16 LDS: thread t owns row co=t (32 floats)
    {
        const float4* src = (const float4*)(cw + (size_t)t * RR);
        #pragma unroll
        for (int g = 0; g < 8; g++) {
            float4 f = src[g];
            union { short4v s; unsigned int u[2]; } s4;
            s4.u[0] = pk_bf16(f.x, f.y);
            s4.u[1] = pk_bf16(f.z, f.w);
            *(short4v*)&CW[t * 36 + g * 4] = s4.s;
        }
    }
    // reduce OP chunks: thread (lane, g=wv) owns regs 4g..4g+3 (bf16 b64 reads)
    int g = wv;
    float s0 = 0.f, s1 = 0.f, s2 = 0.f, s3 = 0.f;
    #pragma unroll
    for (int ch = 0; ch < NCHUNK; ch++) {
        short4v v = *(const short4v*)(OPh + ((base + ch) * 64 + lane) * 16 + 4 * g);
        s0 += bf2f((unsigned short)v[0]); s1 += bf2f((unsigned short)v[1]);
        s2 += bf2f((unsigned short)v[2]); s3 += bf2f((unsigned short)v[3]);
    }
    // softmax denominators (rows i_local = t<32)
    if (t < 32) {
        float sl = 0.f;
        #pragma unroll
        for (int ch = 0; ch < NCHUNK; ch++) {
            sl += LP[(base + ch) * 64 + t] + LP[(base + ch) * 64 + t + 32];
        }
        linv[t] = 1.f / sl;
    }
    __syncthreads();   // linv + CW ready
    {
        float sv[4] = {s0, s1, s2, s3};
        #pragma unroll
        for (int j = 0; j < 4; j++) {
            int reg = 4 * g + j;
            int il = (reg & 3) + 8 * (reg >> 2) + 4 * h;   // C/D row mapping
            Ft[il][l31] = f2bf(sv[j] * linv[il]);          // r = l31 channel
        }
    }
    __syncthreads();   // Ft ready
    // convout: wave wv does co-tiles 2wv, 2wv+1
    #pragma unroll
    for (int cti = 0; cti < 2; cti++) {
        int co0 = (wv * 2 + cti) * 32;
        const unsigned short* arow = &CW[(co0 + l31) * 36 + 8 * h];
        union { short8 s; short4v hh[2]; } a1, a2, b1, b2;
        a1.hh[0] = *(const short4v*)arow;
        a1.hh[1] = *(const short4v*)(arow + 4);
        a2.hh[0] = *(const short4v*)(arow + 16);
        a2.hh[1] = *(const short4v*)(arow + 20);
        const unsigned short* brow = &Ft[l31][8 * h];
        b1.hh[0] = *(const short4v*)brow;
        b1.hh[1] = *(const short4v*)(brow + 4);
        b2.hh[0] = *(const short4v*)(brow + 16);
        b2.hh[1] = *(const short4v*)(brow + 20);
        floatx16 acc = {};
        acc = __builtin_amdgcn_mfma_f32_32x32x16_bf16(a1.s, b1.s, acc, 0, 0, 0);
        acc = __builtin_amdgcn_mfma_f32_32x32x16_bf16(a2.s, b2.s, acc, 0, 0, 0);
        #pragma unroll
        for (int rr = 0; rr < 16; rr++) {
            int co = co0 + (rr & 3) + 8 * (rr >> 2) + 4 * h;
            size_t o = ((size_t)(b * CC + co)) * NN + itile * 32 + l31;
            out[o] = x[o] + acc[rr] + cb[co];
        }
    }
}

extern "C" void kernel_launch(void* const* d_in, const int* in_sizes, int n_in,
                              void* d_out, int out_size, void* d_ws, size_t ws_size,
                              hipStream_t stream) {
    const float* x = (const float*)d_in[0];
    char* ws = (char*)d_ws;
    // D (24 MB, dead after k_pw) aliases OPh (8 MB bf16, written by k_attn)
    unsigned short* Dq  = (unsigned short*)(ws);              // 24 MB [p][b][c][n]
    unsigned short* OPh = (unsigned short*)(ws);              // 8 MB (alias of D)
    unsigned short* Qt  = (unsigned short*)(ws + 25165824);   // 1 MB (b,n,r)
    unsigned short* Kt  = (unsigned short*)(ws + 26214400);   // 1 MB (b,n,r)
    unsigned short* V   = (unsigned short*)(ws + 27262976);   // 1 MB (b,r,n)
    float*          LP  = (float*)(ws + 28311552);            // 1 MB

    hipLaunchKernelGGL(k_dw, dim3(CC, BB), dim3(256), 0, stream, x,
                       (const float*)d_in[1], (const float*)d_in[2],
                       (const float*)d_in[5], (const float*)d_in[6],
                       (const float*)d_in[9], (const float*)d_in[10], Dq);
    hipLaunchKernelGGL(k_pw, dim3(32, 3, BB), dim3(256), 0, stream, Dq,
                       (const float*)d_in[3], (const float*)d_in[4],
                       (const float*)d_in[7], (const float*)d_in[8],
                       (const float*)d_in[11], (const float*)d_in[12],
                       V, Qt, Kt);
    hipLaunchKernelGGL(k_attn, dim3(16, NCHUNK, BB), dim3(256), 0, stream,
                       Qt, Kt, V, OPh, LP);
    hipLaunchKernelGGL(k_out, dim3(128, BB), dim3(256), 0, stream,
                       x, OPh, LP, (const float*)d_in[13], (const float*)d_in[14],
                       (float*)d_out);
}

// Round 6
// 137.502 us; speedup vs baseline: 1.0182x; 1.0165x over previous
//
#include <hip/hip_runtime.h>
#include <stdint.h>

#define BB 4
#define CC 256
#define NN 4096   // H*W = 64*64
#define RR 32
#define NCHUNK 8
#define JSTEPS (NN / NCHUNK / 32)   // 16
#define CSIZE  (NN / NCHUNK)        // 512

typedef __attribute__((ext_vector_type(8)))  short  short8;   // 8 bf16 (MFMA A/B frag)
typedef __attribute__((ext_vector_type(4)))  short  short4v;  // 4 bf16 = 8B
typedef __attribute__((ext_vector_type(16))) float  floatx16; // MFMA C/D frag

#if defined(__has_builtin)
#if __has_builtin(__builtin_amdgcn_cvt_pk_bf16_f32)
#define HAVE_PK_BF16 1
#endif
#endif

#ifdef HAVE_PK_BF16
typedef __attribute__((ext_vector_type(2))) __bf16 bf16x2;
#endif

static __device__ __forceinline__ unsigned short f2bf_sw(float f) {
    union { float f; unsigned int u; } v; v.f = f;
    unsigned int u = v.u;
    u += 0x7fffu + ((u >> 16) & 1u);
    return (unsigned short)(u >> 16);
}

// pack two fp32 -> bf16x2 in one HW inst (lo = a, hi = b)
static __device__ __forceinline__ unsigned int pk_bf16(float a, float b) {
#ifdef HAVE_PK_BF16
    bf16x2 r = __builtin_amdgcn_cvt_pk_bf16_f32(a, b);
    unsigned int u; __builtin_memcpy(&u, &r, 4); return u;
#else
    return (unsigned int)f2bf_sw(a) | ((unsigned int)f2bf_sw(b) << 16);
#endif
}

static __device__ __forceinline__ unsigned short f2bf(float f) {
#ifdef HAVE_PK_BF16
    return (unsigned short)(pk_bf16(f, 0.f) & 0xffffu);
#else
    return f2bf_sw(f);
#endif
}

static __device__ __forceinline__ float bf2f(unsigned short u) {
    union { unsigned int u; float f; } v; v.u = ((unsigned int)u) << 16;
    return v.f;
}

static __device__ __forceinline__ float exp2_fast(float x) {
#if __has_builtin(__builtin_amdgcn_exp2f)
    return __builtin_amdgcn_exp2f(x);
#else
    return exp2f(x);
#endif
}

// ---------------- K1: depthwise 3x3, all 3 dilations -> D bf16 --------------
// grid (C, B), block 256 = 4 waves; wave = 16-h strip, lane = w. 26 x-rows in
// registers (x read exactly once); horizontal taps via shfl (CSE'd per phase).
// D layout: [p][b][c][n] bf16.
__global__ __launch_bounds__(256, 4) void k_dw(
    const float* __restrict__ x,
    const float* __restrict__ w1, const float* __restrict__ b1,
    const float* __restrict__ w2, const float* __restrict__ b2,
    const float* __restrict__ w3, const float* __restrict__ b3,
    unsigned short* __restrict__ Dq)
{
    int t = threadIdx.x, lane = t & 63, wv = t >> 6;
    int c = blockIdx.x, b = blockIdx.y;
    int hb = wv * 16;
    const float* xc = x + ((size_t)(b * CC + c)) * NN;
    float row[26];
    #pragma unroll
    for (int k = 0; k < 26; k++) {
        int rr = hb - 5 + k;
        int rc = rr < 0 ? 0 : (rr > 63 ? 63 : rr);
        float v = xc[rc * 64 + lane];
        row[k] = (rr >= 0 && rr <= 63) ? v : 0.f;
    }
    const float* DWW[3] = {w1, w2, w3};
    const float* DWB[3] = {b1, b2, b3};
    #pragma unroll
    for (int p = 0; p < 3; p++) {
        const int d = (p == 0) ? 1 : (p == 1 ? 3 : 5);
        float wt[9];
        #pragma unroll
        for (int q = 0; q < 9; q++) wt[q] = DWW[p][c * 9 + q];
        float bias = DWB[p][c];
        bool okl = lane >= d, okr = lane < 64 - d;
        int lml = okl ? lane - d : 0;
        int lpr = okr ? lane + d : 63;
        float sm[26], sp[26];
        #pragma unroll
        for (int k = 5 - d; k <= 20 + d; k++) {
            float a = __shfl(row[k], lml, 64); sm[k] = okl ? a : 0.f;
            float q2 = __shfl(row[k], lpr, 64); sp[k] = okr ? q2 : 0.f;
        }
        unsigned short* Dp = Dq + (((size_t)p * BB + b) * CC + c) * NN;
        #pragma unroll
        for (int hl = 0; hl < 16; hl++) {
            int k0 = hl + 5 - d, k1 = hl + 5, k2 = hl + 5 + d;
            float o = bias
                + wt[0] * sm[k0] + wt[1] * row[k0] + wt[2] * sp[k0]
                + wt[3] * sm[k1] + wt[4] * row[k1] + wt[5] * sp[k1]
                + wt[6] * sm[k2] + wt[7] * row[k2] + wt[8] * sp[k2];
            Dp[(hb + hl) * 64 + lane] = f2bf(o);
        }
    }
}

// ---------------- K2: pointwise C->R as MFMA GEMM, LDS-staged B -------------
// grid (32 ntiles of 128 n, 3 p, B), block 256 = 4 waves; wave = 32r x 32n.
// K=256 in two 128-c halves staged into LDS; A = pw bf16 (LDS-staged).
__global__ __launch_bounds__(256, 2) void k_pw(
    const unsigned short* __restrict__ Dq,
    const float* __restrict__ p1, const float* __restrict__ pb1,
    const float* __restrict__ p2, const float* __restrict__ pb2,
    const float* __restrict__ p3, const float* __restrict__ pb3,
    unsigned short* __restrict__ V, unsigned short* __restrict__ Qt,
    unsigned short* __restrict__ Kt)
{
    __shared__ unsigned short PW[32 * 264];        // pw bf16, row stride 264
    __shared__ unsigned short Dt[128 * 132];       // D half-tile [c128][n128], pad 4
    __shared__ unsigned short Lt[4][32][40];       // per-wave [n][r] transpose buffer
    int t = threadIdx.x, lane = t & 63, l31 = lane & 31, h = lane >> 5, wv = t >> 6;
    int ntile = blockIdx.x, p = blockIdx.y, b = blockIdx.z;
    const float* pw  = (p == 0) ? p1  : (p == 1 ? p2  : p3);
    const float* pwb = (p == 0) ? pb1 : (p == 1 ? pb2 : pb3);

    // stage pw -> bf16 LDS: thread r = t>>3, 32-col block (t&7)*32
    {
        int r = t >> 3, cb0 = (t & 7) * 32;
        const float4* src = (const float4*)(pw + r * CC + cb0);
        #pragma unroll
        for (int g = 0; g < 8; g++) {
            float4 f = src[g];
            union { short4v s; unsigned int u[2]; } s4;
            s4.u[0] = pk_bf16(f.x, f.y);
            s4.u[1] = pk_bf16(f.z, f.w);
            *(short4v*)&PW[r * 264 + cb0 + g * 4] = s4.s;
        }
    }
    __syncthreads();

    int n = ntile * 128 + wv * 32 + l31;
    const size_t dbase = ((size_t)p * BB + b) * CC * (size_t)NN;
    int cr = t >> 1, nseg = (t & 1) * 64;          // staging: row cr, 64-n segment
    floatx16 acc = {};

    for (int hc = 0; hc < 2; hc++) {
        // bulk global load of this c-half's 128B/thread (coalesced, indep)
        const uint4* gsrc = (const uint4*)(Dq + dbase +
                            (size_t)(hc * 128 + cr) * NN + ntile * 128 + nseg);
        uint4 g[8];
        #pragma unroll
        for (int i = 0; i < 8; i++) g[i] = gsrc[i];
        __syncthreads();   // prior half's Dt reads complete
        {
            uint2* ldst = (uint2*)&Dt[cr * 132 + nseg];   // 8B-aligned (264B rows)
            #pragma unroll
            for (int i = 0; i < 8; i++) {
                union { uint4 q; uint2 d2[2]; } u; u.q = g[i];
                ldst[2 * i] = u.d2[0];
                ldst[2 * i + 1] = u.d2[1];
            }
        }
        __syncthreads();   // tile visible
        #pragma unroll
        for (int kt = 0; kt < 8; kt++) {
            short8 af = *(const short8*)&PW[l31 * 264 + hc * 128 + kt * 16 + 8 * h];
            short8 bf;
            #pragma unroll
            for (int j = 0; j < 8; j++)
                bf[j] = (short)Dt[(kt * 16 + 8 * h + j) * 132 + wv * 32 + l31];
            acc = __builtin_amdgcn_mfma_f32_32x32x16_bf16(af, bf, acc, 0, 0, 0);
        }
    }

    if (p == 0) {
        #pragma unroll
        for (int rr = 0; rr < 16; rr++) {
            int r = (rr & 3) + 8 * (rr >> 2) + 4 * h;          // C/D row mapping
            V[((size_t)(b * RR + r)) * NN + n] = f2bf(acc[rr] + pwb[r]);  // V[b][r][n]
        }
    } else {
        const float sc = (p == 1) ? 1.4426950408889634f : 1.f; // Q *= log2e
        unsigned short* outp = (p == 1) ? Qt : Kt;
        #pragma unroll
        for (int rr = 0; rr < 16; rr++) {
            int r = (rr & 3) + 8 * (rr >> 2) + 4 * h;
            Lt[wv][l31][r] = f2bf((acc[rr] + pwb[r]) * sc);
        }
        __threadfence_block();   // order wave-local LDS write->read (lockstep lanes)
        unsigned short* orow = outp + ((size_t)b * NN + n) * RR + h * 16;
        short8 lo = *(const short8*)&Lt[wv][l31][h * 16];
        *(short8*)orow = lo;                                   // [b][n][r], 32B/lane
        short8 hi = *(const short8*)&Lt[wv][l31][h * 16 + 8];
        *(short8*)(orow + 8) = hi;
    }
}

// ---------------- K3: fused attention, dbuf LDS V, quad-permuted frags ------
// grid (16, NCHUNK, B), block 256 = 4 waves. Each wave owns TWO i-tiles
// (itA = bx*4+wave, itB = itA+64). R6: softmax-denominator accumulation split
// into 4 independent partial sums per tile (dependent v_add_f32 chain depth
// 16 -> 4+2; fp adds are not reassociated by the compiler without fast-math,
// and at 2 waves/SIMD the serial chain is poorly hidden).
__global__ __launch_bounds__(256, 2) void k_attn(
    const unsigned short* __restrict__ Qt, const unsigned short* __restrict__ Kt,
    const unsigned short* __restrict__ V, unsigned short* __restrict__ OPh,
    float* __restrict__ LP)
{
    __shared__ unsigned short Vt[2][32][36];   // double buffer
    int t = threadIdx.x;
    int wave = t >> 6, lane = t & 63, l31 = lane & 31, h = lane >> 5;
    int itA = blockIdx.x * 4 + wave;           // 0..63
    int itB = itA + 64;                        // 64..127
    int chunk = blockIdx.y;
    int b = blockIdx.z;
    int iA = itA * 32 + l31;
    int iB = itB * 32 + l31;

    const short8* qrA = (const short8*)(Qt + ((size_t)b * NN + iA) * RR);
    short8 qa1 = qrA[h], qa2 = qrA[2 + h];
    const short8* qrB = (const short8*)(Qt + ((size_t)b * NN + iB) * RR);
    short8 qb1 = qrB[h], qb2 = qrB[2 + h];

    const unsigned short* Kb = Kt + (size_t)b * NN * RR;
    const unsigned short* Vb = V + (size_t)b * RR * NN;

    int sr = t >> 3, sc = t & 7;
    int scp = (sc & 4) | ((sc & 1) << 1) | ((sc & 2) >> 1);  // {0,2,1,3,4,6,5,7}
    const unsigned short* vsrc = Vb + (size_t)sr * NN + chunk * CSIZE + sc * 4;

    floatx16 accA = {}, accB = {};
    float laA0 = 0.f, laA1 = 0.f, laA2 = 0.f, laA3 = 0.f;   // R6: 4-way split
    float laB0 = 0.f, laB1 = 0.f, laB2 = 0.f, laB3 = 0.f;

    // prologue: stage step-0 V tile (permuted), prefetch step-1 V and step-0 K
    *(short4v*)(&Vt[0][sr][scp * 4]) = *(const short4v*)vsrc;
    short4v vnext = *(const short4v*)(vsrc + 32);
    const short8* krow0 = (const short8*)(Kb + (size_t)(chunk * CSIZE + l31) * RR);
    short8 ka1 = krow0[h], ka2 = krow0[2 + h];
    __syncthreads();

    for (int js = 0; js < JSTEPS; js++) {
        int cur = js & 1;
        if (js + 1 < JSTEPS) *(short4v*)(&Vt[1 - cur][sr][scp * 4]) = vnext;
        if (js + 2 < JSTEPS) vnext = *(const short4v*)(vsrc + (js + 2) * 32);

        // shared V B-frags for this j-step (permuted rows: contiguous b128)
        const unsigned short* vrow = &Vt[cur][l31][0];
        short8 vb1 = *(const short8*)(vrow + 8 * h);
        short8 vb2 = *(const short8*)(vrow + 16 + 8 * h);

        // ---- itile A ----
        {
            floatx16 st = {};
            st = __builtin_amdgcn_mfma_f32_32x32x16_bf16(ka1, qa1, st, 0, 0, 0);
            st = __builtin_amdgcn_mfma_f32_32x32x16_bf16(ka2, qa2, st, 0, 0, 0);
            float p[16];
            #pragma unroll
            for (int r = 0; r < 16; r++) p[r] = exp2_fast(st[r]);
            #pragma unroll
            for (int r = 0; r < 4; r++) {       // 4 independent chains, depth 4
                laA0 += p[r];
                laA1 += p[r + 4];
                laA2 += p[r + 8];
                laA3 += p[r + 12];
            }
            union { short8 s; unsigned int u[4]; } pa1, pa2;
            #pragma unroll
            for (int r = 0; r < 8; r += 2) {
                pa1.u[r >> 1] = pk_bf16(p[r], p[r + 1]);
                pa2.u[r >> 1] = pk_bf16(p[r + 8], p[r + 9]);
            }
            accA = __builtin_amdgcn_mfma_f32_32x32x16_bf16(pa1.s, vb1, accA, 0, 0, 0);
            accA = __builtin_amdgcn_mfma_f32_32x32x16_bf16(pa2.s, vb2, accA, 0, 0, 0);
        }

        // ---- itile B (ka still live; prefetch next K after its S-MFMAs) ----
        {
            floatx16 st = {};
            st = __builtin_amdgcn_mfma_f32_32x32x16_bf16(ka1, qb1, st, 0, 0, 0);
            st = __builtin_amdgcn_mfma_f32_32x32x16_bf16(ka2, qb2, st, 0, 0, 0);
            int jn = (js + 1 < JSTEPS) ? js + 1 : js;
            const short8* krow = (const short8*)(Kb + (size_t)(chunk * CSIZE + jn * 32 + l31) * RR);
            ka1 = krow[h]; ka2 = krow[2 + h];
            float p[16];
            #pragma unroll
            for (int r = 0; r < 16; r++) p[r] = exp2_fast(st[r]);
            #pragma unroll
            for (int r = 0; r < 4; r++) {       // 4 independent chains, depth 4
                laB0 += p[r];
                laB1 += p[r + 4];
                laB2 += p[r + 8];
                laB3 += p[r + 12];
            }
            union { short8 s; unsigned int u[4]; } pa1, pa2;
            #pragma unroll
            for (int r = 0; r < 8; r += 2) {
                pa1.u[r >> 1] = pk_bf16(p[r], p[r + 1]);
                pa2.u[r >> 1] = pk_bf16(p[r + 8], p[r + 9]);
            }
            accB = __builtin_amdgcn_mfma_f32_32x32x16_bf16(pa1.s, vb1, accB, 0, 0, 0);
            accB = __builtin_amdgcn_mfma_f32_32x32x16_bf16(pa2.s, vb2, accB, 0, 0, 0);
        }
        __syncthreads();   // reads of Vt[cur] done; Vt[1-cur] visible for js+1
    }

    // epilogue: both itiles
    {
        size_t slot = ((size_t)(b * 128 + itA) * NCHUNK + chunk) * 64 + lane;
        unsigned short* op = OPh + slot * 16;
        union { short8 s; unsigned int u[4]; } o1, o2;
        #pragma unroll
        for (int r = 0; r < 8; r += 2) {
            o1.u[r >> 1] = pk_bf16(accA[r], accA[r + 1]);
            o2.u[r >> 1] = pk_bf16(accA[r + 8], accA[r + 9]);
        }
        *(short8*)op = o1.s;
        *(short8*)(op + 8) = o2.s;
        LP[slot] = (laA0 + laA1) + (laA2 + laA3);
    }
    {
        size_t slot = ((size_t)(b * 128 + itB) * NCHUNK + chunk) * 64 + lane;
        unsigned short* op = OPh + slot * 16;
        union { short8 s; unsigned int u[4]; } o1, o2;
        #pragma unroll
        for (int r = 0; r < 8; r += 2) {
            o1.u[r >> 1] = pk_bf16(accB[r], accB[r + 1]);
            o2.u[r >> 1] = pk_bf16(accB[r + 8], accB[r + 9]);
        }
        *(short8*)op = o1.s;
        *(short8*)(op + 8) = o2.s;
        LP[slot] = (laB0 + laB1) + (laB2 + laB3);
    }
}

// ---------------- K4: fused merge + 1x1 conv R->C + residual ----------------
// grid (128 itiles, B), block 256. Reduce bf16 OP chunks in-register -> Ft
// tile in LDS -> 8x mfma vs LDS-staged cw -> out = x + conv + bias.
__global__ __launch_bounds__(256, 4) void k_out(
    const float* __restrict__ x, const unsigned short* __restrict__ OPh,
    const float* __restrict__ LP, const float* __restrict__ cw,
    const float* __restrict__ cb, float* __restrict__ out)
{
    __shared__ float linv[32];
    __shared__ unsigned short Ft[32][36];     // [n_local][r]
    __shared__ unsigned short CW[256 * 36];   // cw bf16, row stride 36
    int t = threadIdx.x, lane = t & 63, l31 = lane & 31, h = lane >> 5, wv = t >> 6;
    int itile = blockIdx.x, b = blockIdx.y;
    size_t base = (size_t)(b * 128 + itile) * NCHUNK;

    // stage cw -> bf16 LDS: thread t owns row co=t (32 floats)
    {
        const float4* src = (const float4*)(cw + (size_t)t * RR);
        #pragma unroll
        for (int g = 0; g < 8; g++) {
            float4 f = src[g];
            union { short4v s; unsigned int u[2]; } s4;
            s4.u[0] = pk_bf16(f.x, f.y);
            s4.u[1] = pk_bf16(f.z, f.w);
            *(short4v*)&CW[t * 36 + g * 4] = s4.s;
        }
    }
    // reduce OP chunks: thread (lane, g=wv) owns regs 4g..4g+3 (bf16 b64 reads)
    int g = wv;
    float s0 = 0.f, s1 = 0.f, s2 = 0.f, s3 = 0.f;
    #pragma unroll
    for (int ch = 0; ch < NCHUNK; ch++) {
        short4v v = *(const short4v*)(OPh + ((base + ch) * 64 + lane) * 16 + 4 * g);
        s0 += bf2f((unsigned short)v[0]); s1 += bf2f((unsigned short)v[1]);
        s2 += bf2f((unsigned short)v[2]); s3 += bf2f((unsigned short)v[3]);
    }
    // softmax denominators (rows i_local = t<32)
    if (t < 32) {
        float sl = 0.f;
        #pragma unroll
        for (int ch = 0; ch < NCHUNK; ch++) {
            sl += LP[(base + ch) * 64 + t] + LP[(base + ch) * 64 + t + 32];
        }
        linv[t] = 1.f / sl;
    }
    __syncthreads();   // linv + CW ready
    {
        float sv[4] = {s0, s1, s2, s3};
        #pragma unroll
        for (int j = 0; j < 4; j++) {
            int reg = 4 * g + j;
            int il = (reg & 3) + 8 * (reg >> 2) + 4 * h;   // C/D row mapping
            Ft[il][l31] = f2bf(sv[j] * linv[il]);          // r = l31 channel
        }
    }
    __syncthreads();   // Ft ready
    // convout: wave wv does co-tiles 2wv, 2wv+1
    #pragma unroll
    for (int cti = 0; cti < 2; cti++) {
        int co0 = (wv * 2 + cti) * 32;
        const unsigned short* arow = &CW[(co0 + l31) * 36 + 8 * h];
        union { short8 s; short4v hh[2]; } a1, a2, b1, b2;
        a1.hh[0] = *(const short4v*)arow;
        a1.hh[1] = *(const short4v*)(arow + 4);
        a2.hh[0] = *(const short4v*)(arow + 16);
        a2.hh[1] = *(const short4v*)(arow + 20);
        const unsigned short* brow = &Ft[l31][8 * h];
        b1.hh[0] = *(const short4v*)brow;
        b1.hh[1] = *(const short4v*)(brow + 4);
        b2.hh[0] = *(const short4v*)(brow + 16);
        b2.hh[1] = *(const short4v*)(brow + 20);
        floatx16 acc = {};
        acc = __builtin_amdgcn_mfma_f32_32x32x16_bf16(a1.s, b1.s, acc, 0, 0, 0);
        acc = __builtin_amdgcn_mfma_f32_32x32x16_bf16(a2.s, b2.s, acc, 0, 0, 0);
        #pragma unroll
        for (int rr = 0; rr < 16; rr++) {
            int co = co0 + (rr & 3) + 8 * (rr >> 2) + 4 * h;
            size_t o = ((size_t)(b * CC + co)) * NN + itile * 32 + l31;
            out[o] = x[o] + acc[rr] + cb[co];
        }
    }
}

extern "C" void kernel_launch(void* const* d_in, const int* in_sizes, int n_in,
                              void* d_out, int out_size, void* d_ws, size_t ws_size,
                              hipStream_t stream) {
    const float* x = (const float*)d_in[0];
    char* ws = (char*)d_ws;
    // D (24 MB, dead after k_pw) aliases OPh (8 MB bf16, written by k_attn)
    unsigned short* Dq  = (unsigned short*)(ws);              // 24 MB [p][b][c][n]
    unsigned short* OPh = (unsigned short*)(ws);              // 8 MB (alias of D)
    unsigned short* Qt  = (unsigned short*)(ws + 25165824);   // 1 MB (b,n,r)
    unsigned short* Kt  = (unsigned short*)(ws + 26214400);   // 1 MB (b,n,r)
    unsigned short* V   = (unsigned short*)(ws + 27262976);   // 1 MB (b,r,n)
    float*          LP  = (float*)(ws + 28311552);            // 1 MB

    hipLaunchKernelGGL(k_dw, dim3(CC, BB), dim3(256), 0, stream, x,
                       (const float*)d_in[1], (const float*)d_in[2],
                       (const float*)d_in[5], (const float*)d_in[6],
                       (const float*)d_in[9], (const float*)d_in[10], Dq);
    hipLaunchKernelGGL(k_pw, dim3(32, 3, BB), dim3(256), 0, stream, Dq,
                       (const float*)d_in[3], (const float*)d_in[4],
                       (const float*)d_in[7], (const float*)d_in[8],
                       (const float*)d_in[11], (const float*)d_in[12],
                       V, Qt, Kt);
    hipLaunchKernelGGL(k_attn, dim3(16, NCHUNK, BB), dim3(256), 0, stream,
                       Qt, Kt, V, OPh, LP);
    hipLaunchKernelGGL(k_out, dim3(128, BB), dim3(256), 0, stream,
                       x, OPh, LP, (const float*)d_in[13], (const float*)d_in[14],
                       (float*)d_out);
}